// Round 4
// baseline (649.958 us; speedup 1.0000x reference)
//
#include <hip/hip_runtime.h>
#include <hip/hip_bf16.h>
#include <cstdint>
#include <cstddef>

#define IN_DIM 512
#define HID 256
#define OUTD 64
#define NEG_SLOPE 0.2f

typedef __attribute__((ext_vector_type(8))) __bf16 bfrag_t;      // MFMA A/B operand (8 bf16 = 4 VGPR)
typedef __attribute__((ext_vector_type(4))) float facc_t;        // MFMA C/D (4 fp32)
typedef __attribute__((ext_vector_type(4))) unsigned int u32x4;  // 16B copies

__device__ __forceinline__ float bf2f(unsigned short u) {
  return __uint_as_float(((unsigned int)u) << 16);
}
__device__ __forceinline__ unsigned short f2bf(float f) {
  unsigned int x = __float_as_uint(f);
  x = (x + 0x7FFFu + ((x >> 16) & 1u)) >> 16;  // RNE
  return (unsigned short)x;
}

// ---------------- MFMA GEMM, B^T layout: C[m,n] = sum_k A[m,k] * B[n,k] ----------------
// A: [M,K] row-major, fp32 if a32 else bf16. B: [N,K] row-major bf16.
// C: [M,N], fp32 if c32 else bf16. K % 32 == 0, N % BN == 0.
// Block = 256 threads = 4 waves in 2x2; wave tile = (BM/2)x(BN/2) of 16x16 frags.
template <int BM, int BN>
__global__ __launch_bounds__(256) void gemm_bt(const void* __restrict__ Araw,
                                               const unsigned short* __restrict__ B,
                                               void* __restrict__ Craw,
                                               int M, int N, int K, int a32, int c32) {
  constexpr int FM = BM / 32, FN = BN / 32;
  constexpr int LDT = 40;  // 32 + 8 pad (2-way bank aliasing = free)
  __shared__ __align__(16) unsigned short lds[(BM + BN) * LDT];

  const int bm0 = blockIdx.x * BM;
  const int bn0 = blockIdx.y * BN;
  const int tid = threadIdx.x;
  const int lane = tid & 63;
  const int wave = tid >> 6;
  const int wrow = (wave >> 1) * (BM / 2);
  const int wcol = (wave & 1) * (BN / 2);
  const int lr = lane & 15;
  const int quad = lane >> 4;

  facc_t acc[FM][FN];
#pragma unroll
  for (int i = 0; i < FM; ++i)
#pragma unroll
    for (int j = 0; j < FN; ++j) acc[i][j] = (facc_t){0.f, 0.f, 0.f, 0.f};

  for (int k0 = 0; k0 < K; k0 += 32) {
    __syncthreads();
    // stage A rows [0,BM) and B rows [BM,BM+BN): 32 bf16 per row as 4x(8-elem) segments
    for (int s = tid; s < (BM + BN) * 4; s += 256) {
      const int row = s >> 2, sub = s & 3;
      if (row < BM) {
        int gm = bm0 + row;
        if (gm >= M) gm = M - 1;  // clamp (stores guarded later)
        const size_t base = (size_t)gm * K + k0 + sub * 8;
        if (a32) {
          const float* sp = (const float*)Araw + base;
          const float4 f0 = *(const float4*)sp;
          const float4 f1 = *(const float4*)(sp + 4);
          u32x4 pk;
          pk.x = (unsigned int)f2bf(f0.x) | ((unsigned int)f2bf(f0.y) << 16);
          pk.y = (unsigned int)f2bf(f0.z) | ((unsigned int)f2bf(f0.w) << 16);
          pk.z = (unsigned int)f2bf(f1.x) | ((unsigned int)f2bf(f1.y) << 16);
          pk.w = (unsigned int)f2bf(f1.z) | ((unsigned int)f2bf(f1.w) << 16);
          *(u32x4*)&lds[row * LDT + sub * 8] = pk;
        } else {
          *(u32x4*)&lds[row * LDT + sub * 8] =
              *(const u32x4*)((const unsigned short*)Araw + base);
        }
      } else {
        const int gn = bn0 + (row - BM);
        *(u32x4*)&lds[row * LDT + sub * 8] = *(const u32x4*)&B[(size_t)gn * K + k0 + sub * 8];
      }
    }
    __syncthreads();

    bfrag_t a[FM], b[FN];
#pragma unroll
    for (int i = 0; i < FM; ++i)
      a[i] = *(const bfrag_t*)&lds[(wrow + i * 16 + lr) * LDT + quad * 8];
#pragma unroll
    for (int j = 0; j < FN; ++j)
      b[j] = *(const bfrag_t*)&lds[(BM + wcol + j * 16 + lr) * LDT + quad * 8];
#pragma unroll
    for (int i = 0; i < FM; ++i)
#pragma unroll
      for (int j = 0; j < FN; ++j)
        acc[i][j] = __builtin_amdgcn_mfma_f32_16x16x32_bf16(a[i], b[j], acc[i][j], 0, 0, 0);
  }

  // C/D layout: col=lane&15, row=quad*4+reg  [verified m89/m91]
#pragma unroll
  for (int i = 0; i < FM; ++i)
#pragma unroll
    for (int r = 0; r < 4; ++r) {
      const int grow = bm0 + wrow + i * 16 + quad * 4 + r;
      if (grow < M) {
#pragma unroll
        for (int j = 0; j < FN; ++j) {
          const int gcol = bn0 + wcol + j * 16 + lr;
          if (c32) ((float*)Craw)[(size_t)grow * N + gcol] = acc[i][j][r];
          else ((unsigned short*)Craw)[(size_t)grow * N + gcol] = f2bf(acc[i][j][r]);
        }
      }
    }
}

// ---------------- weight prep (fp32 in -> bf16 out) ----------------
__global__ void cvt_straight(const float* __restrict__ in, unsigned short* __restrict__ out,
                             int nelem) {
  const int i = blockIdx.x * 256 + threadIdx.x;
  if (i < nelem) out[i] = f2bf(in[i]);
}

__global__ void transpose_cvt(const float* __restrict__ in, unsigned short* __restrict__ out,
                              int R, int C) {
  const int idx = blockIdx.x * 256 + threadIdx.x;
  if (idx >= R * C) return;
  const int r = idx / C, c = idx % C;
  out[(size_t)c * R + r] = f2bf(in[idx]);
}

// a_s[i] = hp1[i,:] . att_src ; a_d[i] = hp1[i,:] . att_dst   (one wave per node)
__global__ __launch_bounds__(256) void rowdot(const unsigned short* __restrict__ hp,
                                              const float* __restrict__ att_s,
                                              const float* __restrict__ att_d,
                                              float* __restrict__ as_, float* __restrict__ ad_,
                                              int n) {
  const int node = blockIdx.x * 4 + (threadIdx.x >> 6);
  if (node >= n) return;
  const int lane = threadIdx.x & 63;
  const unsigned short* row = hp + (size_t)node * HID + (lane << 2);
  float s = 0.f, d = 0.f;
#pragma unroll
  for (int j = 0; j < 4; ++j) {
    const float h = bf2f(row[j]);
    s += h * att_s[(lane << 2) + j];
    d += h * att_d[(lane << 2) + j];
  }
  for (int off = 32; off > 0; off >>= 1) {
    s += __shfl_down(s, off);
    d += __shfl_down(d, off);
  }
  if (lane == 0) { as_[node] = s; ad_[node] = d; }
}

__global__ void init_nodes(float* __restrict__ denom, int* __restrict__ deg, int n) {
  const int i = blockIdx.x * 256 + threadIdx.x;
  if (i < n) {
    denom[i] = 0.f;
    deg[i] = 0;
  }
}

// per-edge exp(leaky_relu(logit)); softmax is shift-invariant, clamp makes overflow impossible
__global__ void edge_pass1(const int* __restrict__ src, const int* __restrict__ dst,
                           const float* __restrict__ as_, const float* __restrict__ ad_,
                           float* __restrict__ eexp, float* __restrict__ denom,
                           int* __restrict__ deg, int E, int n) {
  const int e = blockIdx.x * 256 + threadIdx.x;
  if (e >= E) return;
  const int s = src[e], d = dst[e];
  if ((unsigned)s >= (unsigned)n || (unsigned)d >= (unsigned)n) return;
  float l = as_[s] + ad_[d];
  l = l > 0.f ? l : NEG_SLOPE * l;
  const float ex = expf(fminf(l, 60.f));
  eexp[e] = ex;
  atomicAdd(&denom[d], ex);
  atomicAdd(&deg[d], 1);
}

// single-block scan of deg -> row_ptr (exclusive), cursor = row start. 8 elems/thread/chunk.
__global__ __launch_bounds__(1024) void scan_kernel(const int* __restrict__ deg,
                                                    int* __restrict__ row_ptr,
                                                    int* __restrict__ cursor, int n) {
  __shared__ int sm[1024];
  __shared__ int carry;
  const int tid = threadIdx.x;
  if (tid == 0) { carry = 0; row_ptr[0] = 0; }
  __syncthreads();
  for (int base = 0; base < n; base += 8192) {
    int v[8];
    int s = 0;
#pragma unroll
    for (int j = 0; j < 8; ++j) {
      const int i = base + tid * 8 + j;
      v[j] = (i < n) ? deg[i] : 0;
      s += v[j];
    }
    sm[tid] = s;
    __syncthreads();
    for (int off = 1; off < 1024; off <<= 1) {
      const int t = (tid >= off) ? sm[tid - off] : 0;
      __syncthreads();
      sm[tid] += t;
      __syncthreads();
    }
    const int c = carry;
    int run = sm[tid] - s + c;
#pragma unroll
    for (int j = 0; j < 8; ++j) {
      const int i = base + tid * 8 + j;
      if (i < n) {
        cursor[i] = run;
        row_ptr[i + 1] = run + v[j];
      }
      run += v[j];
    }
    __syncthreads();
    if (tid == 0) carry = c + sm[1023];
    __syncthreads();
  }
}

__global__ void edge_scatter(const int* __restrict__ src, const int* __restrict__ dst,
                             const float* __restrict__ eexp, const float* __restrict__ denom,
                             int* __restrict__ cursor, int* __restrict__ csr_src,
                             float* __restrict__ csr_w, int E, int n) {
  const int e = blockIdx.x * 256 + threadIdx.x;
  if (e >= E) return;
  const int s = src[e], d = dst[e];
  if ((unsigned)s >= (unsigned)n || (unsigned)d >= (unsigned)n) return;
  const float w = eexp[e] / (denom[d] + 1e-16f);
  const int pos = atomicAdd(&cursor[d], 1);
  csr_src[pos] = s;
  csr_w[pos] = w;
}

// out[d,:] = elu( sum_e w_e * hpre[src_e,:] )  — one wave per dst node, 4 fp32 acc/lane
__global__ __launch_bounds__(256) void gat_prop(const unsigned short* __restrict__ hpre,
                                                const int* __restrict__ row_ptr,
                                                const int* __restrict__ csr_src,
                                                const float* __restrict__ csr_w,
                                                unsigned short* __restrict__ out, int n) {
  const int node = blockIdx.x * 4 + (threadIdx.x >> 6);
  if (node >= n) return;
  const int lane = threadIdx.x & 63;
  const int beg = row_ptr[node], end = row_ptr[node + 1];
  float a0 = 0.f, a1 = 0.f, a2 = 0.f, a3 = 0.f;
  for (int e = beg; e < end; ++e) {
    const int s = csr_src[e];
    const float w = csr_w[e];
    const uint2 v = *(const uint2*)(hpre + (size_t)s * HID + (lane << 2));
    a0 += w * bf2f((unsigned short)(v.x & 0xffffu));
    a1 += w * bf2f((unsigned short)(v.x >> 16));
    a2 += w * bf2f((unsigned short)(v.y & 0xffffu));
    a3 += w * bf2f((unsigned short)(v.y >> 16));
  }
  a0 = a0 > 0.f ? a0 : (expf(a0) - 1.f);
  a1 = a1 > 0.f ? a1 : (expf(a1) - 1.f);
  a2 = a2 > 0.f ? a2 : (expf(a2) - 1.f);
  a3 = a3 > 0.f ? a3 : (expf(a3) - 1.f);
  uint2 o;
  o.x = (unsigned int)f2bf(a0) | ((unsigned int)f2bf(a1) << 16);
  o.y = (unsigned int)f2bf(a2) | ((unsigned int)f2bf(a3) << 16);
  *(uint2*)(out + (size_t)node * HID + (lane << 2)) = o;
}

extern "C" void kernel_launch(void* const* d_in, const int* in_sizes, int n_in,
                              void* d_out, int out_size, void* d_ws, size_t ws_size,
                              hipStream_t stream) {
  const float* feat = (const float*)d_in[0];   // [N, 512] fp32
  const float* W1 = (const float*)d_in[1];     // [512, 256] fp32
  const float* W2 = (const float*)d_in[2];     // [256, 64] fp32
  const float* att_s = (const float*)d_in[3];  // [256] fp32
  const float* att_d = (const float*)d_in[4];  // [256] fp32
  const int* ei = (const int*)d_in[5];         // [2, E] int32
  const int N = in_sizes[0] / IN_DIM;          // 50000
  const int E = in_sizes[5] / 2;               // 600000
  const int* src = ei;
  const int* dst = ei + E;
  float* outf = (float*)d_out;  // h2 [N,64] ++ h4 [N,512], fp32 (reference output dtype)

  // hp1/hp3 (bf16 [N,256] each = N*512 B each) park inside the not-yet-written h4 slot
  // (N*512 fp32 = N*2048 B). Lifetimes strictly sequential; conv4 overwrites the slot
  // last and reads only h1h3 (workspace) + W1b.
  unsigned short* hp1 = (unsigned short*)(outf + (size_t)N * OUTD);
  unsigned short* hp3 = hp1 + (size_t)N * HID;

  // ---- workspace carve-up (~35 MB, 256B-aligned) ----
  char* w = (char*)d_ws;
  size_t off = 0;
  auto alloc = [&](size_t bytes) -> void* {
    void* p = w + off;
    off += (bytes + 255) & ~(size_t)255;
    return p;
  };
  unsigned short* h1h3 = (unsigned short*)alloc((size_t)N * HID * 2);  // h1, then h3
  float* a_src_v = (float*)alloc((size_t)N * 4);
  float* a_dst_v = (float*)alloc((size_t)N * 4);
  float* eexp = (float*)alloc((size_t)E * 4);
  float* denom = (float*)alloc((size_t)N * 4);
  int* deg = (int*)alloc((size_t)N * 4);
  int* row_ptr = (int*)alloc((size_t)(N + 1) * 4);
  int* cursor = (int*)alloc((size_t)N * 4);
  int* csr_src = (int*)alloc((size_t)E * 4);
  float* csr_w = (float*)alloc((size_t)E * 4);
  unsigned short* W1T = (unsigned short*)alloc((size_t)IN_DIM * HID * 2);  // [256,512] bf16
  unsigned short* W1b = (unsigned short*)alloc((size_t)IN_DIM * HID * 2);  // [512,256] bf16
  unsigned short* W2T = (unsigned short*)alloc((size_t)HID * OUTD * 2);    // [64,256] bf16
  unsigned short* W2b = (unsigned short*)alloc((size_t)HID * OUTD * 2);    // [256,64] bf16

  const int EB = (E + 255) / 256;
  const int NB = (N + 255) / 256;
  const int MB = (N + 127) / 128;

  // bf16 weight copies, both orientations (B^T-form GEMM wants B rows of length K)
  transpose_cvt<<<(IN_DIM * HID + 255) / 256, 256, 0, stream>>>(W1, W1T, IN_DIM, HID);
  cvt_straight<<<(IN_DIM * HID + 255) / 256, 256, 0, stream>>>(W1, W1b, IN_DIM * HID);
  transpose_cvt<<<(HID * OUTD + 255) / 256, 256, 0, stream>>>(W2, W2T, HID, OUTD);
  cvt_straight<<<(HID * OUTD + 255) / 256, 256, 0, stream>>>(W2, W2b, HID * OUTD);

  // conv1: hp1 = feat @ W1   [N,256]   (A fp32 -> bf16 repack in staging; C bf16)
  gemm_bt<128, 128><<<dim3(MB, HID / 128), 256, 0, stream>>>(feat, W1T, hp1, N, HID, IN_DIM,
                                                             1, 0);
  rowdot<<<(N + 3) / 4, 256, 0, stream>>>(hp1, att_s, att_d, a_src_v, a_dst_v, N);

  // edge softmax (tied: shared by conv1 & conv3) + dst-CSR build
  init_nodes<<<NB, 256, 0, stream>>>(denom, deg, N);
  edge_pass1<<<EB, 256, 0, stream>>>(src, dst, a_src_v, a_dst_v, eexp, denom, deg, E, N);
  scan_kernel<<<1, 1024, 0, stream>>>(deg, row_ptr, cursor, N);
  edge_scatter<<<EB, 256, 0, stream>>>(src, dst, eexp, denom, cursor, csr_src, csr_w, E, N);

  // conv1 propagate + elu -> h1 (bf16)
  gat_prop<<<(N + 3) / 4, 256, 0, stream>>>(hp1, row_ptr, csr_src, csr_w, h1h3, N);
  // conv2: h2 = h1 @ W2 -> outf[0 : N*64]  (C fp32)
  gemm_bt<128, 64><<<dim3(MB, OUTD / 64), 256, 0, stream>>>(h1h3, W2T, outf, N, OUTD, HID,
                                                            0, 1);
  // conv3: hp3 = h2 @ W2^T   (A = h2 fp32; B = W2 as stored; C bf16)
  gemm_bt<128, 128><<<dim3(MB, HID / 128), 256, 0, stream>>>(outf, W2b, hp3, N, HID, OUTD,
                                                             1, 0);
  // conv3 propagate + elu -> h3 (bf16)
  gat_prop<<<(N + 3) / 4, 256, 0, stream>>>(hp3, row_ptr, csr_src, csr_w, h1h3, N);
  // conv4: h4 = h3 @ W1^T -> outf[N*64 : ]  (C fp32)
  gemm_bt<128, 128><<<dim3(MB, IN_DIM / 128), 256, 0, stream>>>(h1h3, W1b,
                                                                outf + (size_t)N * OUTD,
                                                                N, IN_DIM, HID, 0, 1);
}

// Round 5
// 563.059 us; speedup vs baseline: 1.1543x; 1.1543x over previous
//
#include <hip/hip_runtime.h>
#include <hip/hip_bf16.h>
#include <cstdint>
#include <cstddef>

#define IN_DIM 512
#define HID 256
#define OUTD 64
#define NEG_SLOPE 0.2f

typedef __attribute__((ext_vector_type(8))) __bf16 bfrag_t;      // MFMA A/B operand
typedef __attribute__((ext_vector_type(4))) float facc_t;        // MFMA C/D
typedef __attribute__((ext_vector_type(4))) unsigned int u32x4;  // 16B copies

__device__ __forceinline__ float bf2f(unsigned short u) {
  return __uint_as_float(((unsigned int)u) << 16);
}
__device__ __forceinline__ unsigned short f2bf(float f) {
  unsigned int x = __float_as_uint(f);
  x = (x + 0x7FFFu + ((x >> 16) & 1u)) >> 16;  // RNE
  return (unsigned short)x;
}

// async global->LDS 16B/lane; LDS dst is wave-uniform base + lane*16 [m97/m104]
#define GLOAD_LDS16(g, l)                                              \
  __builtin_amdgcn_global_load_lds(                                    \
      (const __attribute__((address_space(1))) void*)(g),              \
      (__attribute__((address_space(3))) void*)(l), 16, 0, 0)

// ---------------- MFMA GEMM, B^T layout: C[m,n] = sum_k A[m,k] * B[n,k] ----------------
// A: [M,K] bf16. B: [N,K] bf16. C: fp32 if c32 else bf16; optional extra bf16 copy Cb.
// K % 32 == 0, N % BN == 0. Block = 256 = 4 waves (2x2 wave grid).
// Staging: global_load_lds width-16, unpadded 64 B rows, seg^(row&3) source swizzle
// (cuts frag-read bank conflicts 8-way -> 4-way; 2-way is free per m136).
template <int BM, int BN>
__global__ __launch_bounds__(256) void gemm_bt(const unsigned short* __restrict__ A,
                                               const unsigned short* __restrict__ B,
                                               void* __restrict__ Craw,
                                               unsigned short* __restrict__ Cb,
                                               int M, int N, int K, int c32) {
  constexpr int FM = BM / 32, FN = BN / 32;
  constexpr int RT = BM + BN;
  __shared__ __align__(16) unsigned short lds[RT * 32];

  const int bm0 = blockIdx.x * BM;
  const int bn0 = blockIdx.y * BN;
  const int tid = threadIdx.x;
  const int lane = tid & 63;
  const int wave = tid >> 6;
  const int wrow = (wave >> 1) * (BM / 2);
  const int wcol = (wave & 1) * (BN / 2);
  const int lr = lane & 15;
  const int quad = lane >> 4;
  const int swz = (quad ^ (lr & 3)) << 3;  // swizzled 8-elem slot within 32-elem row

  facc_t acc[FM][FN];
#pragma unroll
  for (int i = 0; i < FM; ++i)
#pragma unroll
    for (int j = 0; j < FN; ++j) acc[i][j] = (facc_t){0.f, 0.f, 0.f, 0.f};

  for (int k0 = 0; k0 < K; k0 += 32) {
    __syncthreads();  // previous iter's ds_reads done before overwrite
    // stage RT rows x 32 bf16 (64 B/row): instr t covers rows [t*16, t*16+16)
#pragma unroll
    for (int t = wave; t < RT / 16; t += 4) {
      const int r0 = t * 16;  // uniform per instr; A/B split is 16-row aligned
      const int row = r0 + (lane >> 2);
      const int seg = (lane & 3) ^ (row & 3);
      const unsigned short* g;
      if (r0 < BM) {
        int gm = bm0 + row;
        if (gm >= M) gm = M - 1;  // clamp; stores guarded in epilogue
        g = A + (size_t)gm * K + k0 + seg * 8;
      } else {
        g = B + (size_t)(bn0 + row - BM) * K + k0 + seg * 8;
      }
      GLOAD_LDS16(g, lds + t * 512);
    }
    __syncthreads();  // compiler drains vmcnt(0) before barrier

    bfrag_t a[FM], b[FN];
#pragma unroll
    for (int i = 0; i < FM; ++i)
      a[i] = *(const bfrag_t*)&lds[(wrow + i * 16 + lr) * 32 + swz];
#pragma unroll
    for (int j = 0; j < FN; ++j)
      b[j] = *(const bfrag_t*)&lds[(BM + wcol + j * 16 + lr) * 32 + swz];
#pragma unroll
    for (int i = 0; i < FM; ++i)
#pragma unroll
      for (int j = 0; j < FN; ++j)
        acc[i][j] = __builtin_amdgcn_mfma_f32_16x16x32_bf16(a[i], b[j], acc[i][j], 0, 0, 0);
  }

  // C/D layout: col=lane&15, row=quad*4+reg  [verified m89/m91]
#pragma unroll
  for (int i = 0; i < FM; ++i)
#pragma unroll
    for (int r = 0; r < 4; ++r) {
      const int grow = bm0 + wrow + i * 16 + quad * 4 + r;
      if (grow < M) {
#pragma unroll
        for (int j = 0; j < FN; ++j) {
          const int gcol = bn0 + wcol + j * 16 + lr;
          const float v = acc[i][j][r];
          if (c32) ((float*)Craw)[(size_t)grow * N + gcol] = v;
          else ((unsigned short*)Craw)[(size_t)grow * N + gcol] = f2bf(v);
          if (Cb) Cb[(size_t)grow * N + gcol] = f2bf(v);
        }
      }
    }
}

// ---------------- conversions ----------------
// 8 elems/thread fp32 -> bf16 (vectorized)
__global__ void cvt_feat(const float* __restrict__ in, unsigned short* __restrict__ out,
                         int n8) {
  const int i = blockIdx.x * 256 + threadIdx.x;
  if (i >= n8) return;
  const float4 f0 = ((const float4*)in)[i * 2];
  const float4 f1 = ((const float4*)in)[i * 2 + 1];
  u32x4 pk;
  pk.x = (unsigned int)f2bf(f0.x) | ((unsigned int)f2bf(f0.y) << 16);
  pk.y = (unsigned int)f2bf(f0.z) | ((unsigned int)f2bf(f0.w) << 16);
  pk.z = (unsigned int)f2bf(f1.x) | ((unsigned int)f2bf(f1.y) << 16);
  pk.w = (unsigned int)f2bf(f1.z) | ((unsigned int)f2bf(f1.w) << 16);
  ((u32x4*)out)[i] = pk;
}

__global__ void cvt_straight(const float* __restrict__ in, unsigned short* __restrict__ out,
                             int nelem) {
  const int i = blockIdx.x * 256 + threadIdx.x;
  if (i < nelem) out[i] = f2bf(in[i]);
}

__global__ void transpose_cvt(const float* __restrict__ in, unsigned short* __restrict__ out,
                              int R, int C) {
  const int idx = blockIdx.x * 256 + threadIdx.x;
  if (idx >= R * C) return;
  const int r = idx / C, c = idx % C;
  out[(size_t)c * R + r] = f2bf(in[idx]);
}

// a_s[i] = hp1[i,:] . att_src ; a_d[i] = hp1[i,:] . att_dst   (one wave per node)
__global__ __launch_bounds__(256) void rowdot(const unsigned short* __restrict__ hp,
                                              const float* __restrict__ att_s,
                                              const float* __restrict__ att_d,
                                              float* __restrict__ as_, float* __restrict__ ad_,
                                              int n) {
  const int node = blockIdx.x * 4 + (threadIdx.x >> 6);
  if (node >= n) return;
  const int lane = threadIdx.x & 63;
  const unsigned short* row = hp + (size_t)node * HID + (lane << 2);
  float s = 0.f, d = 0.f;
#pragma unroll
  for (int j = 0; j < 4; ++j) {
    const float h = bf2f(row[j]);
    s += h * att_s[(lane << 2) + j];
    d += h * att_d[(lane << 2) + j];
  }
  for (int off = 32; off > 0; off >>= 1) {
    s += __shfl_down(s, off);
    d += __shfl_down(d, off);
  }
  if (lane == 0) { as_[node] = s; ad_[node] = d; }
}

__global__ void init_nodes(float* __restrict__ denom, int* __restrict__ deg, int n) {
  const int i = blockIdx.x * 256 + threadIdx.x;
  if (i < n) {
    denom[i] = 0.f;
    deg[i] = 0;
  }
}

// per-edge exp(leaky_relu(logit)); softmax is shift-invariant, clamp kills overflow
__global__ void edge_pass1(const int* __restrict__ src, const int* __restrict__ dst,
                           const float* __restrict__ as_, const float* __restrict__ ad_,
                           float* __restrict__ eexp, float* __restrict__ denom,
                           int* __restrict__ deg, int E, int n) {
  const int e = blockIdx.x * 256 + threadIdx.x;
  if (e >= E) return;
  const int s = src[e], d = dst[e];
  if ((unsigned)s >= (unsigned)n || (unsigned)d >= (unsigned)n) return;
  float l = as_[s] + ad_[d];
  l = l > 0.f ? l : NEG_SLOPE * l;
  const float ex = expf(fminf(l, 60.f));
  eexp[e] = ex;
  atomicAdd(&denom[d], ex);
  atomicAdd(&deg[d], 1);
}

// single-block scan: deg -> row_ptr (exclusive) + cursor. shfl wave-scan, 2 barriers/chunk.
__global__ __launch_bounds__(1024) void scan_kernel(const int* __restrict__ deg,
                                                    int* __restrict__ row_ptr,
                                                    int* __restrict__ cursor, int n) {
  __shared__ int wsum[16];
  __shared__ int carry;
  const int tid = threadIdx.x, lane = tid & 63, wid = tid >> 6;
  if (tid == 0) { carry = 0; row_ptr[0] = 0; }
  __syncthreads();
  for (int base = 0; base < n; base += 8192) {
    int v[8], s = 0;
#pragma unroll
    for (int j = 0; j < 8; ++j) {
      const int i = base + tid * 8 + j;
      v[j] = (i < n) ? deg[i] : 0;
      s += v[j];
    }
    int ws = s;  // wave-inclusive scan of per-thread sums
    for (int off = 1; off < 64; off <<= 1) {
      const int t = __shfl_up(ws, off);
      if (lane >= off) ws += t;
    }
    if (lane == 63) wsum[wid] = ws;
    __syncthreads();
    if (wid == 0 && lane < 16) {
      int t = wsum[lane];
      for (int off = 1; off < 16; off <<= 1) {
        const int u = __shfl_up(t, off);
        if (lane >= off) t += u;
      }
      wsum[lane] = t;
    }
    __syncthreads();
    int run = carry + (wid ? wsum[wid - 1] : 0) + (ws - s);
#pragma unroll
    for (int j = 0; j < 8; ++j) {
      const int i = base + tid * 8 + j;
      if (i < n) {
        cursor[i] = run;
        row_ptr[i + 1] = run + v[j];
      }
      run += v[j];
    }
    __syncthreads();
    if (tid == 0) carry += wsum[15];
    __syncthreads();
  }
}

__global__ void edge_scatter(const int* __restrict__ src, const int* __restrict__ dst,
                             const float* __restrict__ eexp, const float* __restrict__ denom,
                             int* __restrict__ cursor, int* __restrict__ csr_src,
                             float* __restrict__ csr_w, int E, int n) {
  const int e = blockIdx.x * 256 + threadIdx.x;
  if (e >= E) return;
  const int s = src[e], d = dst[e];
  if ((unsigned)s >= (unsigned)n || (unsigned)d >= (unsigned)n) return;
  const float w = eexp[e] / (denom[d] + 1e-16f);
  const int pos = atomicAdd(&cursor[d], 1);
  csr_src[pos] = s;
  csr_w[pos] = w;
}

// out[d,:] = elu( sum_e w_e * hpre[src_e,:] ) — one wave/node; edge loop unrolled x4
__global__ __launch_bounds__(256) void gat_prop(const unsigned short* __restrict__ hpre,
                                                const int* __restrict__ row_ptr,
                                                const int* __restrict__ csr_src,
                                                const float* __restrict__ csr_w,
                                                unsigned short* __restrict__ out, int n) {
  const int node = blockIdx.x * 4 + (threadIdx.x >> 6);
  if (node >= n) return;
  const int lane = threadIdx.x & 63;
  const int beg = row_ptr[node], end = row_ptr[node + 1];
  const unsigned short* rowbase = hpre + (size_t)(lane << 2);
  float a0 = 0.f, a1 = 0.f, a2 = 0.f, a3 = 0.f;
  int e = beg;
  for (; e + 4 <= end; e += 4) {
    const int s0 = csr_src[e], s1 = csr_src[e + 1], s2 = csr_src[e + 2], s3 = csr_src[e + 3];
    const float w0 = csr_w[e], w1 = csr_w[e + 1], w2 = csr_w[e + 2], w3 = csr_w[e + 3];
    const uint2 v0 = *(const uint2*)(rowbase + (size_t)s0 * HID);
    const uint2 v1 = *(const uint2*)(rowbase + (size_t)s1 * HID);
    const uint2 v2 = *(const uint2*)(rowbase + (size_t)s2 * HID);
    const uint2 v3 = *(const uint2*)(rowbase + (size_t)s3 * HID);
    a0 += w0 * bf2f((unsigned short)(v0.x & 0xffffu)) + w1 * bf2f((unsigned short)(v1.x & 0xffffu))
        + w2 * bf2f((unsigned short)(v2.x & 0xffffu)) + w3 * bf2f((unsigned short)(v3.x & 0xffffu));
    a1 += w0 * bf2f((unsigned short)(v0.x >> 16)) + w1 * bf2f((unsigned short)(v1.x >> 16))
        + w2 * bf2f((unsigned short)(v2.x >> 16)) + w3 * bf2f((unsigned short)(v3.x >> 16));
    a2 += w0 * bf2f((unsigned short)(v0.y & 0xffffu)) + w1 * bf2f((unsigned short)(v1.y & 0xffffu))
        + w2 * bf2f((unsigned short)(v2.y & 0xffffu)) + w3 * bf2f((unsigned short)(v3.y & 0xffffu));
    a3 += w0 * bf2f((unsigned short)(v0.y >> 16)) + w1 * bf2f((unsigned short)(v1.y >> 16))
        + w2 * bf2f((unsigned short)(v2.y >> 16)) + w3 * bf2f((unsigned short)(v3.y >> 16));
  }
  for (; e < end; ++e) {
    const int s = csr_src[e];
    const float w = csr_w[e];
    const uint2 v = *(const uint2*)(rowbase + (size_t)s * HID);
    a0 += w * bf2f((unsigned short)(v.x & 0xffffu));
    a1 += w * bf2f((unsigned short)(v.x >> 16));
    a2 += w * bf2f((unsigned short)(v.y & 0xffffu));
    a3 += w * bf2f((unsigned short)(v.y >> 16));
  }
  a0 = a0 > 0.f ? a0 : (expf(a0) - 1.f);
  a1 = a1 > 0.f ? a1 : (expf(a1) - 1.f);
  a2 = a2 > 0.f ? a2 : (expf(a2) - 1.f);
  a3 = a3 > 0.f ? a3 : (expf(a3) - 1.f);
  uint2 o;
  o.x = (unsigned int)f2bf(a0) | ((unsigned int)f2bf(a1) << 16);
  o.y = (unsigned int)f2bf(a2) | ((unsigned int)f2bf(a3) << 16);
  *(uint2*)(out + (size_t)node * HID + (lane << 2)) = o;
}

extern "C" void kernel_launch(void* const* d_in, const int* in_sizes, int n_in,
                              void* d_out, int out_size, void* d_ws, size_t ws_size,
                              hipStream_t stream) {
  const float* feat = (const float*)d_in[0];   // [N, 512] fp32
  const float* W1 = (const float*)d_in[1];     // [512, 256] fp32
  const float* W2 = (const float*)d_in[2];     // [256, 64] fp32
  const float* att_s = (const float*)d_in[3];  // [256] fp32
  const float* att_d = (const float*)d_in[4];  // [256] fp32
  const int* ei = (const int*)d_in[5];         // [2, E] int32
  const int N = in_sizes[0] / IN_DIM;          // 50000
  const int E = in_sizes[5] / 2;               // 600000
  const int* src = ei;
  const int* dst = ei + E;
  float* outf = (float*)d_out;  // h2 [N,64] fp32 ++ h4 [N,512] fp32

  // Park featb/hp1/hp3 in the not-yet-written h4 slot (N*512*4 B = 51.2+25.6+25.6 MB
  // exactly). Lifetimes strictly sequential: featb dead after conv1; hp1 dead after
  // gat_prop1; hp3 dead after gat_prop2; conv4 writes the slot last reading only ws.
  unsigned short* featb = (unsigned short*)(outf + (size_t)N * OUTD);  // [N,512] bf16
  unsigned short* hp1 = featb + (size_t)N * IN_DIM;                    // [N,256] bf16
  unsigned short* hp3 = hp1 + (size_t)N * HID;                         // [N,256] bf16

  // ---- workspace carve-up (~41 MB, 256B-aligned) ----
  char* w = (char*)d_ws;
  size_t off = 0;
  auto alloc = [&](size_t bytes) -> void* {
    void* p = w + off;
    off += (bytes + 255) & ~(size_t)255;
    return p;
  };
  unsigned short* h1h3 = (unsigned short*)alloc((size_t)N * HID * 2);  // h1, then h3
  unsigned short* h2b = (unsigned short*)alloc((size_t)N * OUTD * 2);  // h2 bf16
  float* a_src_v = (float*)alloc((size_t)N * 4);
  float* a_dst_v = (float*)alloc((size_t)N * 4);
  float* eexp = (float*)alloc((size_t)E * 4);
  float* denom = (float*)alloc((size_t)N * 4);
  int* deg = (int*)alloc((size_t)N * 4);
  int* row_ptr = (int*)alloc((size_t)(N + 1) * 4);
  int* cursor = (int*)alloc((size_t)N * 4);
  int* csr_src = (int*)alloc((size_t)E * 4);
  float* csr_w = (float*)alloc((size_t)E * 4);
  unsigned short* W1T = (unsigned short*)alloc((size_t)IN_DIM * HID * 2);  // [256,512] bf16
  unsigned short* W1b = (unsigned short*)alloc((size_t)IN_DIM * HID * 2);  // [512,256] bf16
  unsigned short* W2T = (unsigned short*)alloc((size_t)HID * OUTD * 2);    // [64,256] bf16
  unsigned short* W2b = (unsigned short*)alloc((size_t)HID * OUTD * 2);    // [256,64] bf16

  const int EB = (E + 255) / 256;
  const int NB = (N + 255) / 256;
  const int MB = (N + 127) / 128;

  // input conversions
  cvt_feat<<<(N * IN_DIM / 8 + 255) / 256, 256, 0, stream>>>(feat, featb, N * IN_DIM / 8);
  transpose_cvt<<<(IN_DIM * HID + 255) / 256, 256, 0, stream>>>(W1, W1T, IN_DIM, HID);
  cvt_straight<<<(IN_DIM * HID + 255) / 256, 256, 0, stream>>>(W1, W1b, IN_DIM * HID);
  transpose_cvt<<<(HID * OUTD + 255) / 256, 256, 0, stream>>>(W2, W2T, HID, OUTD);
  cvt_straight<<<(HID * OUTD + 255) / 256, 256, 0, stream>>>(W2, W2b, HID * OUTD);

  // conv1: hp1 = feat @ W1   [N,256] bf16
  gemm_bt<128, 128><<<dim3(MB, HID / 128), 256, 0, stream>>>(featb, W1T, hp1, nullptr,
                                                             N, HID, IN_DIM, 0);
  rowdot<<<(N + 3) / 4, 256, 0, stream>>>(hp1, att_s, att_d, a_src_v, a_dst_v, N);

  // edge softmax (tied: shared by conv1 & conv3) + dst-CSR build
  init_nodes<<<NB, 256, 0, stream>>>(denom, deg, N);
  edge_pass1<<<EB, 256, 0, stream>>>(src, dst, a_src_v, a_dst_v, eexp, denom, deg, E, N);
  scan_kernel<<<1, 1024, 0, stream>>>(deg, row_ptr, cursor, N);
  edge_scatter<<<EB, 256, 0, stream>>>(src, dst, eexp, denom, cursor, csr_src, csr_w, E, N);

  // conv1 propagate + elu -> h1 (bf16)
  gat_prop<<<(N + 3) / 4, 256, 0, stream>>>(hp1, row_ptr, csr_src, csr_w, h1h3, N);
  // conv2: h2 = h1 @ W2 -> outf (fp32) + h2b (bf16)
  gemm_bt<128, 64><<<dim3(MB, OUTD / 64), 256, 0, stream>>>(h1h3, W2T, outf, h2b,
                                                            N, OUTD, HID, 1);
  // conv3: hp3 = h2 @ W2^T  (B = W2 as stored)
  gemm_bt<128, 128><<<dim3(MB, HID / 128), 256, 0, stream>>>(h2b, W2b, hp3, nullptr,
                                                             N, HID, OUTD, 0);
  // conv3 propagate + elu -> h3 (bf16)
  gat_prop<<<(N + 3) / 4, 256, 0, stream>>>(hp3, row_ptr, csr_src, csr_w, h1h3, N);
  // conv4: h4 = h3 @ W1^T -> outf[N*64:] (fp32)
  gemm_bt<128, 128><<<dim3(MB, IN_DIM / 128), 256, 0, stream>>>(h1h3, W1b,
                                                                outf + (size_t)N * OUTD,
                                                                nullptr, N, IN_DIM, HID, 1);
}